// Round 20
// baseline (136.067 us; speedup 1.0000x reference)
//
#include <hip/hip_runtime.h>
#include <hip/hip_bf16.h>

// KmeansAttention: b=2 h=8 t=8192 d=64 c=64 wsz=128
// A) routing dists: LDS-tiled f64 register-tile GEMM, 512 threads (4 tok x 4 cl
//    per thread, 4 waves/SIMD); means staged f64 in LDS; keys bit-identical
// B) per-(b,h,c) radix-select top-128 (8-bit passes, pass-1 bin compaction);
//    appends each selected token's window-position to per-token list (cnt+plist)
// C) per-window 128x128 MFMA attention; 512 threads, 74.75KB LDS, 2 blocks/CU,
//    native f32->bf16 cvt; v-gather issued before the Gram MFMA loop
// F) per-token gather: out = sum(so rows in plist) / (cnt + 1e-5)
// XCD-aware blockIdx swizzle keeps each bh pair on one XCD's L2 end-to-end.

#define TOKEN_SELF -50000.0f

typedef __attribute__((ext_vector_type(8))) short short8;
typedef __attribute__((ext_vector_type(4))) float f32x4;

__device__ __forceinline__ unsigned short f2bf(float x) {
    union { __hip_bfloat16 b; unsigned short u; } v;
    v.b = __float2bfloat16(x);
    return v.u;
}
__device__ __forceinline__ float bf2f(unsigned short b) {
    return __uint_as_float(((unsigned)b) << 16);
}

// ---------------- Kernel A: routing distances -> sortable u32 keys ----------------
// 1024 blocks x 512 threads. LDS 70.7KB -> 2 blocks/CU (16 waves/CU, 4/SIMD).
__global__ __launch_bounds__(512) void dists_kernel(const float* __restrict__ qk,
                                                    const float* __restrict__ means,
                                                    unsigned* __restrict__ keys) {
    __shared__ float qs[64 * 132];           // [d][tok] 33792 B
    __shared__ double ms[64 * 66];           // [d][c]   33792 B (f64, stride 66)
    __shared__ double rden_s[128];           // 1024 B
    const int lb = ((blockIdx.x & 7) << 7) + (blockIdx.x >> 3);   // XCD swizzle (1024)
    const int tid = threadIdx.x;
    const int bh = lb >> 6;
    const int chunk = lb & 63;
    const int h = bh & 7;
    const int t0 = chunk << 7;

    // stage means[h] transposed as f64: ms[d][c]
    for (int k = tid; k < 1024; k += 512) {
        float4 f = reinterpret_cast<const float4*>(means + h * 4096)[k];
        const int c = k >> 4, d4 = (k & 15) << 2;
        ms[(d4 + 0) * 66 + c] = (double)f.x;
        ms[(d4 + 1) * 66 + c] = (double)f.y;
        ms[(d4 + 2) * 66 + c] = (double)f.z;
        ms[(d4 + 3) * 66 + c] = (double)f.w;
    }
    // stage qk chunk transposed: qs[d][tok]; 4 threads per row, f64 norm via shfl
    {
        const int r = tid >> 2, quarter = tid & 3;   // 16 d's per thread
        const float4* src = reinterpret_cast<const float4*>(
            qk + (((size_t)bh << 13) + t0 + r) * 64 + quarter * 16);
        double n2 = 0.0;
#pragma unroll
        for (int k4 = 0; k4 < 4; ++k4) {
            float4 f = src[k4];
            const int d = quarter * 16 + 4 * k4;
            qs[(d + 0) * 132 + r] = f.x;
            qs[(d + 1) * 132 + r] = f.y;
            qs[(d + 2) * 132 + r] = f.z;
            qs[(d + 3) * 132 + r] = f.w;
            n2 += (double)f.x * (double)f.x + (double)f.y * (double)f.y
                + (double)f.z * (double)f.z + (double)f.w * (double)f.w;
        }
        n2 += __shfl_xor(n2, 1);
        n2 += __shfl_xor(n2, 2);
        if (quarter == 0) {
            double den = sqrt(n2);
            rden_s[r] = 1.0 / (den > 1e-12 ? den : 1e-12);
        }
    }
    __syncthreads();

    // register-tile f64 GEMM: 4 tokens x 4 clusters per thread
    const int tok0 = (tid & 31) << 2;
    const int c0 = (tid >> 5) << 2;      // 16 lane-groups x 4 clusters = 64
    double acc[4][4];
#pragma unroll
    for (int ti = 0; ti < 4; ++ti)
#pragma unroll
        for (int ci = 0; ci < 4; ++ci) acc[ti][ci] = 0.0;

#pragma unroll 2
    for (int d = 0; d < 64; ++d) {
        const float4 qv = *reinterpret_cast<const float4*>(&qs[d * 132 + tok0]);
        const double2 m0 = *reinterpret_cast<const double2*>(&ms[d * 66 + c0 + 0]);
        const double2 m1 = *reinterpret_cast<const double2*>(&ms[d * 66 + c0 + 2]);
        const double qd[4] = {(double)qv.x, (double)qv.y, (double)qv.z, (double)qv.w};
        const double md[4] = {m0.x, m0.y, m1.x, m1.y};
#pragma unroll
        for (int ti = 0; ti < 4; ++ti)
#pragma unroll
            for (int ci = 0; ci < 4; ++ci)
                acc[ti][ci] = fma(qd[ti], md[ci], acc[ti][ci]);
    }

    const double r0 = rden_s[tok0 + 0], r1 = rden_s[tok0 + 1];
    const double r2 = rden_s[tok0 + 2], r3 = rden_s[tok0 + 3];
    unsigned* kb = keys + ((size_t)bh << 19) + t0 + tok0;
#pragma unroll
    for (int ci = 0; ci < 4; ++ci) {
        uint4 wv;
        wv.x = (unsigned)(__double2ll_rn(acc[0][ci] * r0 * 2.0e9) + 2147483648LL);
        wv.y = (unsigned)(__double2ll_rn(acc[1][ci] * r1 * 2.0e9) + 2147483648LL);
        wv.z = (unsigned)(__double2ll_rn(acc[2][ci] * r2 * 2.0e9) + 2147483648LL);
        wv.w = (unsigned)(__double2ll_rn(acc[3][ci] * r3 * 2.0e9) + 2147483648LL);
        *reinterpret_cast<uint4*>(&kb[(size_t)(c0 + ci) << 13]) = wv;
    }
}

// ---------------- Kernel B: exact top-128 per (b,h,c), ascending + list append ----------------
__global__ __launch_bounds__(256) void topk_kernel(const unsigned* __restrict__ keys,
                                                   int* __restrict__ idx_out,
                                                   unsigned short* __restrict__ plist,
                                                   int* __restrict__ cntp) {
    __shared__ __align__(16) unsigned key[8192];   // 32KB
    __shared__ unsigned cand[1024];                // 4KB: pass-1 bin survivors
    __shared__ unsigned hist[256];
    __shared__ int sel[128];                       // selected tokens by slot
    __shared__ unsigned s_prefix, s_need, s_cnt, s_nc;
    __shared__ unsigned wg[4], we[4];
    const int lb = ((blockIdx.x & 7) << 7) + (blockIdx.x >> 3);   // XCD swizzle (1024)
    const int tid = threadIdx.x;
    const int lane = tid & 63;
    const int w = tid >> 6;

    {
        const uint4* src4 = reinterpret_cast<const uint4*>(keys + ((size_t)lb << 13));
        uint4* k4 = reinterpret_cast<uint4*>(key);
        for (int k = tid; k < 2048; k += 256) k4[k] = src4[k];
    }
    __syncthreads();

    unsigned prefix = 0, need = 128u;
    int ncand = -1;
#pragma unroll
    for (int shift = 24; shift >= 0; shift -= 8) {
        hist[tid] = 0u;
        __syncthreads();
        if (shift == 24) {
            for (int k = tid; k < 8192; k += 256) atomicAdd(&hist[key[k] >> 24], 1u);
        } else {
            const unsigned maskHi = 0xFFFFFFFFu << (shift + 8);
            if (ncand >= 0) {
                for (int k = tid; k < ncand; k += 256) {
                    unsigned u = cand[k];
                    if ((u & maskHi) == prefix) atomicAdd(&hist[(u >> shift) & 255u], 1u);
                }
            } else {
                for (int k = tid; k < 8192; k += 256) {
                    unsigned u = key[k];
                    if ((u & maskHi) == prefix) atomicAdd(&hist[(u >> shift) & 255u], 1u);
                }
            }
        }
        __syncthreads();
        if (tid < 64) {
            unsigned h0 = hist[tid*4], h1 = hist[tid*4+1], h2 = hist[tid*4+2], h3 = hist[tid*4+3];
            unsigned tot = h0 + h1 + h2 + h3;
            unsigned s = tot;
#pragma unroll
            for (int off = 1; off < 64; off <<= 1) {
                unsigned tdown = __shfl_down(s, off);
                if (tid + off < 64) s += tdown;
            }
            const unsigned above = s - tot;
            hist[tid*4+3] = above + h3;
            hist[tid*4+2] = above + h3 + h2;
            hist[tid*4+1] = above + h3 + h2 + h1;
            hist[tid*4+0] = above + tot;
        }
        __syncthreads();
        {
            const unsigned sd = hist[tid];
            const unsigned sd1 = (tid < 255) ? hist[tid + 1] : 0u;
            if (sd >= need && sd1 < need) {
                s_prefix = prefix | ((unsigned)tid << shift);
                s_need = need - sd1;
                s_cnt = sd - sd1;
            }
        }
        __syncthreads();
        prefix = s_prefix;
        need = s_need;
        if (shift == 24) {
            const unsigned cd = s_cnt;
            if (tid == 0) s_nc = 0u;
            __syncthreads();
            if (cd <= 1024u) {
                const unsigned D = prefix >> 24;
                for (int k = tid; k < 8192; k += 256) {
                    unsigned u = key[k];
                    if ((u >> 24) == D) cand[atomicAdd(&s_nc, 1u)] = u;
                }
                ncand = (int)cd;
            }
            __syncthreads();
        }
    }

    const unsigned V = prefix;
    const unsigned rneed = need;
    const int base = tid << 5;
    unsigned cgt = 0, ceq = 0;
#pragma unroll 8
    for (int k = 0; k < 32; ++k) {
        unsigned u = key[base + k];
        cgt += (u > V) ? 1u : 0u;
        ceq += (u == V) ? 1u : 0u;
    }
    unsigned gi = cgt, ei = ceq;
#pragma unroll
    for (int off = 1; off < 64; off <<= 1) {
        unsigned tg = __shfl_up(gi, off);
        unsigned te = __shfl_up(ei, off);
        if (lane >= off) { gi += tg; ei += te; }
    }
    if (lane == 63) { wg[w] = gi; we[w] = ei; }
    __syncthreads();
    unsigned og = 0, oe = 0;
    for (int x = 0; x < w; ++x) { og += wg[x]; oe += we[x]; }
    unsigned g = og + gi - cgt;
    unsigned e = oe + ei - ceq;
    int* out = idx_out + (lb << 7);
    for (int k = 0; k < 32; ++k) {
        unsigned u = key[base + k];
        if (u > V) {
            const unsigned slot = g + (e < rneed ? e : rneed);
            out[slot] = base + k;
            sel[slot] = base + k;
            ++g;
        } else if (u == V) {
            if (e < rneed) { out[g + e] = base + k; sel[g + e] = base + k; }
            ++e;
        }
    }
    __syncthreads();
    // ---- append window-position to each selected token's list ----
    if (tid < 128) {
        const int bh = lb >> 6;
        const int tok = sel[tid];
        const int pos = ((lb & 63) << 7) + tid;      // row index within bh's so
        const unsigned s = atomicAdd((unsigned*)&cntp[(bh << 13) + tok], 1u);
        plist[(((size_t)(bh << 13) + tok) << 6) + s] = (unsigned short)pos;
    }
}

// ---------------- Kernel C: windowed MFMA attention -> so ----------------
// 512 threads / 8 waves; each wave owns a 16-row strip.
// LDS: SA = {qhi[128][72], qlo[128][72]} -> {vt_hi[64][136], vt_lo[64][136]}
//      SB = {w[128][72]} -> {g2[128][134]} -> {phi[128][72], plo[128][72]}
__global__ __launch_bounds__(512, 2) void attn_kernel(const float* __restrict__ qk,
                                                      const float* __restrict__ vv,
                                                      const float* __restrict__ relw,
                                                      const int* __restrict__ idx,
                                                      float* __restrict__ so) {
    __shared__ __align__(16) unsigned short SA[18432];
    __shared__ __align__(16) unsigned short SB[18432];
    __shared__ float invn_s[128];
    __shared__ int idxs_s[128];

    const int lb = ((blockIdx.x & 7) << 7) + (blockIdx.x >> 3);   // XCD swizzle (1024)
    const int tid = threadIdx.x;
    const int bh  = lb >> 6;
    const int h   = bh & 7;
    const int wv = tid >> 6, l = tid & 63, g = l >> 4, ln = l & 15;
    const size_t base_bh = ((size_t)bh) << 13;
    const float scale = 0.125f;

    if (tid < 128) idxs_s[tid] = idx[(lb << 7) + tid];
    __syncthreads();

    // ---- P1: gather q -> qhi/qlo + invn; load rel weights -> SB ----
    {
        const int r = tid >> 2, quarter = tid & 3;      // 4 threads per row
        const float4* qsrc = reinterpret_cast<const float4*>(
            qk + (base_bh + idxs_s[r]) * 64 + quarter * 16);
        float x[16]; float nrm = 0.f;
#pragma unroll
        for (int k4 = 0; k4 < 4; ++k4) {
            float4 f = qsrc[k4];
            x[4*k4+0]=f.x; x[4*k4+1]=f.y; x[4*k4+2]=f.z; x[4*k4+3]=f.w;
            nrm += f.x*f.x + f.y*f.y + f.z*f.z + f.w*f.w;
        }
        nrm += __shfl_xor(nrm, 1);
        nrm += __shfl_xor(nrm, 2);
        if (quarter == 0) invn_s[r] = 1.0f / fmaxf(sqrtf(nrm), 1e-12f);
        unsigned short* qhi = SA;
        unsigned short* qlo = SA + 9216;
        const int rb = r * 72 + quarter * 16;
#pragma unroll
        for (int m = 0; m < 8; ++m) {
            unsigned short h0 = f2bf(x[2*m]), h1 = f2bf(x[2*m+1]);
            *(unsigned*)&qhi[rb + 2*m] = (unsigned)h0 | ((unsigned)h1 << 16);
            unsigned short l0 = f2bf(x[2*m] - bf2f(h0));
            unsigned short l1 = f2bf(x[2*m+1] - bf2f(h1));
            *(unsigned*)&qlo[rb + 2*m] = (unsigned)l0 | ((unsigned)l1 << 16);
        }
        float wx[16];
        const float4* wsrc = reinterpret_cast<const float4*>(
            relw + (size_t)(r*8 + h) * 64 + quarter * 16);
#pragma unroll
        for (int k4 = 0; k4 < 4; ++k4) {
            float4 f = wsrc[k4];
            wx[4*k4+0]=f.x; wx[4*k4+1]=f.y; wx[4*k4+2]=f.z; wx[4*k4+3]=f.w;
        }
#pragma unroll
        for (int m = 0; m < 8; ++m) {
            unsigned short w0 = f2bf(wx[2*m]), w1 = f2bf(wx[2*m+1]);
            *(unsigned*)&SB[rb + 2*m] = (unsigned)w0 | ((unsigned)w1 << 16);
        }
    }
    __syncthreads();

    // ---- issue v gather EARLY (latency hides under P2 MFMAs) ----
    const int j0 = (tid & 63) * 2, dbase = (tid >> 6) * 8;
    const float4* vs0 = reinterpret_cast<const float4*>(vv + (base_bh + idxs_s[j0])   * 64 + dbase);
    const float4* vs1 = reinterpret_cast<const float4*>(vv + (base_bh + idxs_s[j0+1]) * 64 + dbase);
    float4 va[2], vb[2];
#pragma unroll
    for (int m = 0; m < 2; ++m) { va[m] = vs0[m]; vb[m] = vs1[m]; }

    // ---- P2: Gram (3-split) + rel MFMAs; wave strip = rows wv*16..wv*16+15 ----
    const unsigned short* qhi = SA;
    const unsigned short* qlo = SA + 9216;
    short8 aH[2], aL[2];
#pragma unroll
    for (int kc = 0; kc < 2; ++kc) {
        int ro = (wv*16 + ln) * 72 + kc*32 + g*8;
        aH[kc] = *(const short8*)&qhi[ro];
        aL[kc] = *(const short8*)&qlo[ro];
    }
    f32x4 accD[8], accG[8];
#pragma unroll
    for (int jt = 0; jt < 8; ++jt) {
        accD[jt] = (f32x4)0.f;
        accG[jt] = (f32x4)0.f;
    }
#pragma unroll
    for (int jt = 0; jt < 8; ++jt) {
        const int rb = (jt*16 + ln) * 72 + g*8;
        short8 bH0 = *(const short8*)&qhi[rb];
        short8 bH1 = *(const short8*)&qhi[rb + 32];
        short8 bL0 = *(const short8*)&qlo[rb];
        short8 bL1 = *(const short8*)&qlo[rb + 32];
        short8 w0  = *(const short8*)&SB[rb];
        short8 w1  = *(const short8*)&SB[rb + 32];
        f32x4 d = accD[jt];
        d = __builtin_amdgcn_mfma_f32_16x16x32_bf16(aH[0], bH0, d, 0, 0, 0);
        d = __builtin_amdgcn_mfma_f32_16x16x32_bf16(aH[1], bH1, d, 0, 0, 0);
        d = __builtin_amdgcn_mfma_f32_16x16x32_bf16(aH[0], bL0, d, 0, 0, 0);
        d = __builtin_amdgcn_mfma_f32_16x16x32_bf16(aH[1], bL1, d, 0, 0, 0);
        d = __builtin_amdgcn_mfma_f32_16x16x32_bf16(aL[0], bH0, d, 0, 0, 0);
        d = __builtin_amdgcn_mfma_f32_16x16x32_bf16(aL[1], bH1, d, 0, 0, 0);
        accD[jt] = d;
        f32x4 gg = accG[jt];
        gg = __builtin_amdgcn_mfma_f32_16x16x32_bf16(aH[0], w0, gg, 0, 0, 0);
        gg = __builtin_amdgcn_mfma_f32_16x16x32_bf16(aH[1], w1, gg, 0, 0, 0);
        accG[jt] = gg;
    }
    __syncthreads();   // q, w dead; SA/SB reusable

    // ---- P3: write g2 (SB) and vt (SA) ----
#pragma unroll
    for (int jt = 0; jt < 8; ++jt) {
        const int i0 = wv*16 + g*4;
        const int c = jt*16 + ln;
#pragma unroll
        for (int r = 0; r < 4; ++r)
            SB[(i0 + r)*134 + c] = f2bf(accG[jt][r]);
    }
    {
        unsigned short* vth = SA;
        unsigned short* vtl = SA + 8704;
#pragma unroll
        for (int m = 0; m < 2; ++m) {
            float pa[4] = {va[m].x, va[m].y, va[m].z, va[m].w};
            float pb[4] = {vb[m].x, vb[m].y, vb[m].z, vb[m].w};
#pragma unroll
            for (int e = 0; e < 4; ++e) {
                const int d = dbase + 4*m + e;
                unsigned short h0 = f2bf(pa[e]), h1 = f2bf(pb[e]);
                *(unsigned*)&vth[d*136 + j0] = (unsigned)h0 | ((unsigned)h1 << 16);
                unsigned short l0 = f2bf(pa[e] - bf2f(h0));
                unsigned short l1 = f2bf(pb[e] - bf2f(h1));
                *(unsigned*)&vtl[d*136 + j0] = (unsigned)l0 | ((unsigned)l1 << 16);
            }
        }
    }
    __syncthreads();

    // ---- P4: epilogue logits + in-register softmax ----
    float invc[8];
#pragma unroll
    for (int jt = 0; jt < 8; ++jt) invc[jt] = invn_s[jt*16 + ln];
    float p[8][4];
#pragma unroll
    for (int jt = 0; jt < 8; ++jt) {
        const int c = jt*16 + ln;
#pragma unroll
        for (int r = 0; r < 4; ++r) {
            const int i = wv*16 + g*4 + r;
            float val = accD[jt][r] * (scale * invc[jt]);
            if (c <= i) val += scale * bf2f(SB[i*134 + (127 + c - i)]);
            if (c == i) val = TOKEN_SELF;
            p[jt][r] = val;
        }
    }
#pragma unroll
    for (int r = 0; r < 4; ++r) {
        float m = p[0][r];
#pragma unroll
        for (int jt = 1; jt < 8; ++jt) m = fmaxf(m, p[jt][r]);
        m = fmaxf(m, __shfl_xor(m, 1));
        m = fmaxf(m, __shfl_xor(m, 2));
        m = fmaxf(m, __shfl_xor(m, 4));
        m = fmaxf(m, __shfl_xor(m, 8));
        float s = 0.f;
#pragma unroll
        for (int jt = 0; jt < 8; ++jt) {
            float e = __expf(p[jt][r] - m);
            p[jt][r] = e;
            s += e;
        }
        s += __shfl_xor(s, 1);
        s += __shfl_xor(s, 2);
        s += __shfl_xor(s, 4);
        s += __shfl_xor(s, 8);
        const float rs = 1.0f / s;
#pragma unroll
        for (int jt = 0; jt < 8; ++jt) p[jt][r] *= rs;
    }

    // ---- P5/P6: PV in two K-halves (P split hi/lo, V split hi/lo) ----
    f32x4 accO[4];
#pragma unroll
    for (int nt = 0; nt < 4; ++nt) accO[nt] = (f32x4)0.f;
    unsigned short* phi = SB;
    unsigned short* plo = SB + 9216;
    const unsigned short* vthc = SA;
    const unsigned short* vtlc = SA + 8704;
#pragma unroll
    for (int kh = 0; kh < 2; ++kh) {
        __syncthreads();   // kh=0: g2 reads done; kh=1: prior A-frag reads done
#pragma unroll
        for (int jtl = 0; jtl < 4; ++jtl) {
            const int jt = kh*4 + jtl;
#pragma unroll
            for (int r = 0; r < 4; ++r) {
                const int i = wv*16 + g*4 + r;
                const int cs = (jtl*16 + ln) ^ (((i >> 2) & 3) << 3);
                const float pv = p[jt][r];
                const unsigned short hb = f2bf(pv);
                phi[i*72 + cs] = hb;
                plo[i*72 + cs] = f2bf(pv - bf2f(hb));
            }
        }
        __syncthreads();
#pragma unroll
        for (int kc = 0; kc < 2; ++kc) {
            const int i = wv*16 + ln;
            const int jb = (kc*32 + g*8) ^ (((ln >> 2) & 3) << 3);
            short8 aPh = *(const short8*)&phi[i*72 + jb];
            short8 aPl = *(const short8*)&plo[i*72 + jb];
#pragma unroll
            for (int nt = 0; nt < 4; ++nt) {
                const int vo = (nt*16 + ln)*136 + kh*64 + kc*32 + g*8;
                short8 bh_ = *(const short8*)&vthc[vo];
                short8 bl_ = *(const short8*)&vtlc[vo];
                f32x4 o = accO[nt];
                o = __builtin_amdgcn_mfma_f32_16x16x32_bf16(aPh, bh_, o, 0, 0, 0);
                o = __builtin_amdgcn_mfma_f32_16x16x32_bf16(aPh, bl_, o, 0, 0, 0);
                o = __builtin_amdgcn_mfma_f32_16x16x32_bf16(aPl, bh_, o, 0, 0, 0);
                accO[nt] = o;
            }
        }
    }

    // ---- P7: plain store of window output ----
    float* dst = so + ((size_t)lb << 13);
#pragma unroll
    for (int nt = 0; nt < 4; ++nt)
#pragma unroll
        for (int r = 0; r < 4; ++r) {
            const int i = wv*16 + g*4 + r;
            dst[(i << 6) + nt*16 + ln] = accO[nt][r];
        }
}

// ---------------- Kernel F: per-token gather + mean (cnt/plist) ----------------
__global__ __launch_bounds__(256) void gather_kernel(const float* __restrict__ so,
                                                     const unsigned short* __restrict__ plist,
                                                     const int* __restrict__ cntp,
                                                     float* __restrict__ out) {
    const int lb = ((blockIdx.x & 7) << 12) + (blockIdx.x >> 3);  // XCD swizzle (32768)
    const int wid = (lb << 2) + (threadIdx.x >> 6);  // token id [0, 131072)
    const int lane = threadIdx.x & 63;
    const int bh = wid >> 13;
    const int tk = wid & 8191;
    const int n = cntp[(bh << 13) + tk];
    float acc = 0.f;
    const float* sob = so + ((size_t)bh << 19);
    const unsigned short* pl = plist + (((size_t)(bh << 13) + tk) << 6);
    for (int e = 0; e < n; ++e) {
        const int p = pl[e];
        acc += sob[((size_t)p << 6) + lane];
    }
    out[((size_t)wid << 6) + lane] = acc / ((float)n + 1e-5f);
}

extern "C" void kernel_launch(void* const* d_in, const int* in_sizes, int n_in,
                              void* d_out, int out_size, void* d_ws, size_t ws_size,
                              hipStream_t stream) {
    const float* qk    = (const float*)d_in[0];
    const float* vv    = (const float*)d_in[1];
    const float* means = (const float*)d_in[2];
    const float* relw  = (const float*)d_in[3];
    float* out = (float*)d_out;

    // ws layout: [keys u32 | so f32] 33.5MB (aliased), idx 0.5MB,
    //            plist u16 16.8MB, cnt 0.5MB  => 51.3MB total
    char* wsb = (char*)d_ws;
    const size_t keyBytes   = (size_t)16 * 64 * 8192 * 4;    // 33,554,432
    const size_t idxBytes   = (size_t)16 * 8192 * 4;         // 524,288
    const size_t plistBytes = (size_t)16 * 8192 * 64 * 2;    // 16,777,216
    unsigned* keys        = (unsigned*)wsb;
    float* so             = (float*)wsb;
    int* idxp             = (int*)(wsb + keyBytes);
    unsigned short* plist = (unsigned short*)(wsb + keyBytes + idxBytes);
    int* cntp             = (int*)(wsb + keyBytes + idxBytes + plistBytes);

    hipMemsetAsync(cntp, 0, (size_t)16 * 8192 * 4, stream);
    dists_kernel<<<1024, 512, 0, stream>>>(qk, means, keys);
    topk_kernel<<<1024, 256, 0, stream>>>(keys, idxp, plist, cntp);
    attn_kernel<<<1024, 512, 0, stream>>>(qk, vv, relw, idxp, so);
    gather_kernel<<<32768, 256, 0, stream>>>(so, plist, cntp, out);
}

// Round 21
// 129.381 us; speedup vs baseline: 1.0517x; 1.0517x over previous
//
#include <hip/hip_runtime.h>
#include <hip/hip_bf16.h>

// KmeansAttention: b=2 h=8 t=8192 d=64 c=64 wsz=128
// A) routing dists: LDS-tiled f64 register-tile GEMM, 512 threads; means staged
//    f64 in LDS; also zeroes cntp (replaces the hipMemsetAsync dispatch)
// B) per-(b,h,c) radix-select top-128 (8-bit passes, pass-1 bin compaction);
//    appends each selected token's window-position to per-token list (cnt+plist)
// C) per-window 128x128 MFMA attention; 512 threads, 74.75KB LDS, 2 blocks/CU,
//    native f32->bf16 cvt; v-gather hoisted; s_setprio(1) around MFMA clusters
//    (T5: 2 blocks/CU at independent phases = the regime where setprio helps)
// F) per-token gather: out = sum(so rows in plist) / (cnt + 1e-5)
// XCD-aware blockIdx swizzle keeps each bh pair on one XCD's L2 end-to-end.

#define TOKEN_SELF -50000.0f

typedef __attribute__((ext_vector_type(8))) short short8;
typedef __attribute__((ext_vector_type(4))) float f32x4;

__device__ __forceinline__ unsigned short f2bf(float x) {
    union { __hip_bfloat16 b; unsigned short u; } v;
    v.b = __float2bfloat16(x);
    return v.u;
}
__device__ __forceinline__ float bf2f(unsigned short b) {
    return __uint_as_float(((unsigned)b) << 16);
}

// ---------------- Kernel A: routing distances -> sortable u32 keys ----------------
// 1024 blocks x 512 threads. LDS 70.7KB -> 2 blocks/CU. Also zeroes cntp.
__global__ __launch_bounds__(512) void dists_kernel(const float* __restrict__ qk,
                                                    const float* __restrict__ means,
                                                    unsigned* __restrict__ keys,
                                                    int* __restrict__ cntp) {
    __shared__ float qs[64 * 132];           // [d][tok] 33792 B
    __shared__ double ms[64 * 66];           // [d][c]   33792 B (f64, stride 66)
    __shared__ double rden_s[128];           // 1024 B
    const int lb = ((blockIdx.x & 7) << 7) + (blockIdx.x >> 3);   // XCD swizzle (1024)
    const int tid = threadIdx.x;
    const int bh = lb >> 6;
    const int chunk = lb & 63;
    const int h = bh & 7;
    const int t0 = chunk << 7;

    // fold-in: zero cntp (16*8192 ints) using the first 256 blocks
    if (blockIdx.x < 256) cntp[((int)blockIdx.x << 9) + tid] = 0;

    // stage means[h] transposed as f64: ms[d][c]
    for (int k = tid; k < 1024; k += 512) {
        float4 f = reinterpret_cast<const float4*>(means + h * 4096)[k];
        const int c = k >> 4, d4 = (k & 15) << 2;
        ms[(d4 + 0) * 66 + c] = (double)f.x;
        ms[(d4 + 1) * 66 + c] = (double)f.y;
        ms[(d4 + 2) * 66 + c] = (double)f.z;
        ms[(d4 + 3) * 66 + c] = (double)f.w;
    }
    // stage qk chunk transposed: qs[d][tok]; 4 threads per row, f64 norm via shfl
    {
        const int r = tid >> 2, quarter = tid & 3;   // 16 d's per thread
        const float4* src = reinterpret_cast<const float4*>(
            qk + (((size_t)bh << 13) + t0 + r) * 64 + quarter * 16);
        double n2 = 0.0;
#pragma unroll
        for (int k4 = 0; k4 < 4; ++k4) {
            float4 f = src[k4];
            const int d = quarter * 16 + 4 * k4;
            qs[(d + 0) * 132 + r] = f.x;
            qs[(d + 1) * 132 + r] = f.y;
            qs[(d + 2) * 132 + r] = f.z;
            qs[(d + 3) * 132 + r] = f.w;
            n2 += (double)f.x * (double)f.x + (double)f.y * (double)f.y
                + (double)f.z * (double)f.z + (double)f.w * (double)f.w;
        }
        n2 += __shfl_xor(n2, 1);
        n2 += __shfl_xor(n2, 2);
        if (quarter == 0) {
            double den = sqrt(n2);
            rden_s[r] = 1.0 / (den > 1e-12 ? den : 1e-12);
        }
    }
    __syncthreads();

    // register-tile f64 GEMM: 4 tokens x 4 clusters per thread
    const int tok0 = (tid & 31) << 2;
    const int c0 = (tid >> 5) << 2;      // 16 lane-groups x 4 clusters = 64
    double acc[4][4];
#pragma unroll
    for (int ti = 0; ti < 4; ++ti)
#pragma unroll
        for (int ci = 0; ci < 4; ++ci) acc[ti][ci] = 0.0;

#pragma unroll 2
    for (int d = 0; d < 64; ++d) {
        const float4 qv = *reinterpret_cast<const float4*>(&qs[d * 132 + tok0]);
        const double2 m0 = *reinterpret_cast<const double2*>(&ms[d * 66 + c0 + 0]);
        const double2 m1 = *reinterpret_cast<const double2*>(&ms[d * 66 + c0 + 2]);
        const double qd[4] = {(double)qv.x, (double)qv.y, (double)qv.z, (double)qv.w};
        const double md[4] = {m0.x, m0.y, m1.x, m1.y};
#pragma unroll
        for (int ti = 0; ti < 4; ++ti)
#pragma unroll
            for (int ci = 0; ci < 4; ++ci)
                acc[ti][ci] = fma(qd[ti], md[ci], acc[ti][ci]);
    }

    const double r0 = rden_s[tok0 + 0], r1 = rden_s[tok0 + 1];
    const double r2 = rden_s[tok0 + 2], r3 = rden_s[tok0 + 3];
    unsigned* kb = keys + ((size_t)bh << 19) + t0 + tok0;
#pragma unroll
    for (int ci = 0; ci < 4; ++ci) {
        uint4 wv;
        wv.x = (unsigned)(__double2ll_rn(acc[0][ci] * r0 * 2.0e9) + 2147483648LL);
        wv.y = (unsigned)(__double2ll_rn(acc[1][ci] * r1 * 2.0e9) + 2147483648LL);
        wv.z = (unsigned)(__double2ll_rn(acc[2][ci] * r2 * 2.0e9) + 2147483648LL);
        wv.w = (unsigned)(__double2ll_rn(acc[3][ci] * r3 * 2.0e9) + 2147483648LL);
        *reinterpret_cast<uint4*>(&kb[(size_t)(c0 + ci) << 13]) = wv;
    }
}

// ---------------- Kernel B: exact top-128 per (b,h,c), ascending + list append ----------------
__global__ __launch_bounds__(256) void topk_kernel(const unsigned* __restrict__ keys,
                                                   int* __restrict__ idx_out,
                                                   unsigned short* __restrict__ plist,
                                                   int* __restrict__ cntp) {
    __shared__ __align__(16) unsigned key[8192];   // 32KB
    __shared__ unsigned cand[1024];                // 4KB: pass-1 bin survivors
    __shared__ unsigned hist[256];
    __shared__ int sel[128];                       // selected tokens by slot
    __shared__ unsigned s_prefix, s_need, s_cnt, s_nc;
    __shared__ unsigned wg[4], we[4];
    const int lb = ((blockIdx.x & 7) << 7) + (blockIdx.x >> 3);   // XCD swizzle (1024)
    const int tid = threadIdx.x;
    const int lane = tid & 63;
    const int w = tid >> 6;

    {
        const uint4* src4 = reinterpret_cast<const uint4*>(keys + ((size_t)lb << 13));
        uint4* k4 = reinterpret_cast<uint4*>(key);
        for (int k = tid; k < 2048; k += 256) k4[k] = src4[k];
    }
    __syncthreads();

    unsigned prefix = 0, need = 128u;
    int ncand = -1;
#pragma unroll
    for (int shift = 24; shift >= 0; shift -= 8) {
        hist[tid] = 0u;
        __syncthreads();
        if (shift == 24) {
            for (int k = tid; k < 8192; k += 256) atomicAdd(&hist[key[k] >> 24], 1u);
        } else {
            const unsigned maskHi = 0xFFFFFFFFu << (shift + 8);
            if (ncand >= 0) {
                for (int k = tid; k < ncand; k += 256) {
                    unsigned u = cand[k];
                    if ((u & maskHi) == prefix) atomicAdd(&hist[(u >> shift) & 255u], 1u);
                }
            } else {
                for (int k = tid; k < 8192; k += 256) {
                    unsigned u = key[k];
                    if ((u & maskHi) == prefix) atomicAdd(&hist[(u >> shift) & 255u], 1u);
                }
            }
        }
        __syncthreads();
        if (tid < 64) {
            unsigned h0 = hist[tid*4], h1 = hist[tid*4+1], h2 = hist[tid*4+2], h3 = hist[tid*4+3];
            unsigned tot = h0 + h1 + h2 + h3;
            unsigned s = tot;
#pragma unroll
            for (int off = 1; off < 64; off <<= 1) {
                unsigned tdown = __shfl_down(s, off);
                if (tid + off < 64) s += tdown;
            }
            const unsigned above = s - tot;
            hist[tid*4+3] = above + h3;
            hist[tid*4+2] = above + h3 + h2;
            hist[tid*4+1] = above + h3 + h2 + h1;
            hist[tid*4+0] = above + tot;
        }
        __syncthreads();
        {
            const unsigned sd = hist[tid];
            const unsigned sd1 = (tid < 255) ? hist[tid + 1] : 0u;
            if (sd >= need && sd1 < need) {
                s_prefix = prefix | ((unsigned)tid << shift);
                s_need = need - sd1;
                s_cnt = sd - sd1;
            }
        }
        __syncthreads();
        prefix = s_prefix;
        need = s_need;
        if (shift == 24) {
            const unsigned cd = s_cnt;
            if (tid == 0) s_nc = 0u;
            __syncthreads();
            if (cd <= 1024u) {
                const unsigned D = prefix >> 24;
                for (int k = tid; k < 8192; k += 256) {
                    unsigned u = key[k];
                    if ((u >> 24) == D) cand[atomicAdd(&s_nc, 1u)] = u;
                }
                ncand = (int)cd;
            }
            __syncthreads();
        }
    }

    const unsigned V = prefix;
    const unsigned rneed = need;
    const int base = tid << 5;
    unsigned cgt = 0, ceq = 0;
#pragma unroll 8
    for (int k = 0; k < 32; ++k) {
        unsigned u = key[base + k];
        cgt += (u > V) ? 1u : 0u;
        ceq += (u == V) ? 1u : 0u;
    }
    unsigned gi = cgt, ei = ceq;
#pragma unroll
    for (int off = 1; off < 64; off <<= 1) {
        unsigned tg = __shfl_up(gi, off);
        unsigned te = __shfl_up(ei, off);
        if (lane >= off) { gi += tg; ei += te; }
    }
    if (lane == 63) { wg[w] = gi; we[w] = ei; }
    __syncthreads();
    unsigned og = 0, oe = 0;
    for (int x = 0; x < w; ++x) { og += wg[x]; oe += we[x]; }
    unsigned g = og + gi - cgt;
    unsigned e = oe + ei - ceq;
    int* out = idx_out + (lb << 7);
    for (int k = 0; k < 32; ++k) {
        unsigned u = key[base + k];
        if (u > V) {
            const unsigned slot = g + (e < rneed ? e : rneed);
            out[slot] = base + k;
            sel[slot] = base + k;
            ++g;
        } else if (u == V) {
            if (e < rneed) { out[g + e] = base + k; sel[g + e] = base + k; }
            ++e;
        }
    }
    __syncthreads();
    // ---- append window-position to each selected token's list ----
    if (tid < 128) {
        const int bh = lb >> 6;
        const int tok = sel[tid];
        const int pos = ((lb & 63) << 7) + tid;      // row index within bh's so
        const unsigned s = atomicAdd((unsigned*)&cntp[(bh << 13) + tok], 1u);
        plist[(((size_t)(bh << 13) + tok) << 6) + s] = (unsigned short)pos;
    }
}

// ---------------- Kernel C: windowed MFMA attention -> so ----------------
// 512 threads / 8 waves; each wave owns a 16-row strip.
// LDS: SA = {qhi[128][72], qlo[128][72]} -> {vt_hi[64][136], vt_lo[64][136]}
//      SB = {w[128][72]} -> {g2[128][134]} -> {phi[128][72], plo[128][72]}
__global__ __launch_bounds__(512, 2) void attn_kernel(const float* __restrict__ qk,
                                                      const float* __restrict__ vv,
                                                      const float* __restrict__ relw,
                                                      const int* __restrict__ idx,
                                                      float* __restrict__ so) {
    __shared__ __align__(16) unsigned short SA[18432];
    __shared__ __align__(16) unsigned short SB[18432];
    __shared__ float invn_s[128];
    __shared__ int idxs_s[128];

    const int lb = ((blockIdx.x & 7) << 7) + (blockIdx.x >> 3);   // XCD swizzle (1024)
    const int tid = threadIdx.x;
    const int bh  = lb >> 6;
    const int h   = bh & 7;
    const int wv = tid >> 6, l = tid & 63, g = l >> 4, ln = l & 15;
    const size_t base_bh = ((size_t)bh) << 13;
    const float scale = 0.125f;

    if (tid < 128) idxs_s[tid] = idx[(lb << 7) + tid];
    __syncthreads();

    // ---- P1: gather q -> qhi/qlo + invn; load rel weights -> SB ----
    {
        const int r = tid >> 2, quarter = tid & 3;      // 4 threads per row
        const float4* qsrc = reinterpret_cast<const float4*>(
            qk + (base_bh + idxs_s[r]) * 64 + quarter * 16);
        float x[16]; float nrm = 0.f;
#pragma unroll
        for (int k4 = 0; k4 < 4; ++k4) {
            float4 f = qsrc[k4];
            x[4*k4+0]=f.x; x[4*k4+1]=f.y; x[4*k4+2]=f.z; x[4*k4+3]=f.w;
            nrm += f.x*f.x + f.y*f.y + f.z*f.z + f.w*f.w;
        }
        nrm += __shfl_xor(nrm, 1);
        nrm += __shfl_xor(nrm, 2);
        if (quarter == 0) invn_s[r] = 1.0f / fmaxf(sqrtf(nrm), 1e-12f);
        unsigned short* qhi = SA;
        unsigned short* qlo = SA + 9216;
        const int rb = r * 72 + quarter * 16;
#pragma unroll
        for (int m = 0; m < 8; ++m) {
            unsigned short h0 = f2bf(x[2*m]), h1 = f2bf(x[2*m+1]);
            *(unsigned*)&qhi[rb + 2*m] = (unsigned)h0 | ((unsigned)h1 << 16);
            unsigned short l0 = f2bf(x[2*m] - bf2f(h0));
            unsigned short l1 = f2bf(x[2*m+1] - bf2f(h1));
            *(unsigned*)&qlo[rb + 2*m] = (unsigned)l0 | ((unsigned)l1 << 16);
        }
        float wx[16];
        const float4* wsrc = reinterpret_cast<const float4*>(
            relw + (size_t)(r*8 + h) * 64 + quarter * 16);
#pragma unroll
        for (int k4 = 0; k4 < 4; ++k4) {
            float4 f = wsrc[k4];
            wx[4*k4+0]=f.x; wx[4*k4+1]=f.y; wx[4*k4+2]=f.z; wx[4*k4+3]=f.w;
        }
#pragma unroll
        for (int m = 0; m < 8; ++m) {
            unsigned short w0 = f2bf(wx[2*m]), w1 = f2bf(wx[2*m+1]);
            *(unsigned*)&SB[rb + 2*m] = (unsigned)w0 | ((unsigned)w1 << 16);
        }
    }
    __syncthreads();

    // ---- issue v gather EARLY (latency hides under P2 MFMAs) ----
    const int j0 = (tid & 63) * 2, dbase = (tid >> 6) * 8;
    const float4* vs0 = reinterpret_cast<const float4*>(vv + (base_bh + idxs_s[j0])   * 64 + dbase);
    const float4* vs1 = reinterpret_cast<const float4*>(vv + (base_bh + idxs_s[j0+1]) * 64 + dbase);
    float4 va[2], vb[2];
#pragma unroll
    for (int m = 0; m < 2; ++m) { va[m] = vs0[m]; vb[m] = vs1[m]; }

    // ---- P2: Gram (3-split) + rel MFMAs; wave strip = rows wv*16..wv*16+15 ----
    const unsigned short* qhi = SA;
    const unsigned short* qlo = SA + 9216;
    short8 aH[2], aL[2];
#pragma unroll
    for (int kc = 0; kc < 2; ++kc) {
        int ro = (wv*16 + ln) * 72 + kc*32 + g*8;
        aH[kc] = *(const short8*)&qhi[ro];
        aL[kc] = *(const short8*)&qlo[ro];
    }
    f32x4 accD[8], accG[8];
#pragma unroll
    for (int jt = 0; jt < 8; ++jt) {
        accD[jt] = (f32x4)0.f;
        accG[jt] = (f32x4)0.f;
    }
    __builtin_amdgcn_s_setprio(1);
#pragma unroll
    for (int jt = 0; jt < 8; ++jt) {
        const int rb = (jt*16 + ln) * 72 + g*8;
        short8 bH0 = *(const short8*)&qhi[rb];
        short8 bH1 = *(const short8*)&qhi[rb + 32];
        short8 bL0 = *(const short8*)&qlo[rb];
        short8 bL1 = *(const short8*)&qlo[rb + 32];
        short8 w0  = *(const short8*)&SB[rb];
        short8 w1  = *(const short8*)&SB[rb + 32];
        f32x4 d = accD[jt];
        d = __builtin_amdgcn_mfma_f32_16x16x32_bf16(aH[0], bH0, d, 0, 0, 0);
        d = __builtin_amdgcn_mfma_f32_16x16x32_bf16(aH[1], bH1, d, 0, 0, 0);
        d = __builtin_amdgcn_mfma_f32_16x16x32_bf16(aH[0], bL0, d, 0, 0, 0);
        d = __builtin_amdgcn_mfma_f32_16x16x32_bf16(aH[1], bL1, d, 0, 0, 0);
        d = __builtin_amdgcn_mfma_f32_16x16x32_bf16(aL[0], bH0, d, 0, 0, 0);
        d = __builtin_amdgcn_mfma_f32_16x16x32_bf16(aL[1], bH1, d, 0, 0, 0);
        accD[jt] = d;
        f32x4 gg = accG[jt];
        gg = __builtin_amdgcn_mfma_f32_16x16x32_bf16(aH[0], w0, gg, 0, 0, 0);
        gg = __builtin_amdgcn_mfma_f32_16x16x32_bf16(aH[1], w1, gg, 0, 0, 0);
        accG[jt] = gg;
    }
    __builtin_amdgcn_s_setprio(0);
    __syncthreads();   // q, w dead; SA/SB reusable

    // ---- P3: write g2 (SB) and vt (SA) ----
#pragma unroll
    for (int jt = 0; jt < 8; ++jt) {
        const int i0 = wv*16 + g*4;
        const int c = jt*16 + ln;
#pragma unroll
        for (int r = 0; r < 4; ++r)
            SB[(i0 + r)*134 + c] = f2bf(accG[jt][r]);
    }
    {
        unsigned short* vth = SA;
        unsigned short* vtl = SA + 8704;
#pragma unroll
        for (int m = 0; m < 2; ++m) {
            float pa[4] = {va[m].x, va[m].y, va[m].z, va[m].w};
            float pb[4] = {vb[m].x, vb[m].y, vb[m].z, vb[m].w};
#pragma unroll
            for (int e = 0; e < 4; ++e) {
                const int d = dbase + 4*m + e;
                unsigned short h0 = f2bf(pa[e]), h1 = f2bf(pb[e]);
                *(unsigned*)&vth[d*136 + j0] = (unsigned)h0 | ((unsigned)h1 << 16);
                unsigned short l0 = f2bf(pa[e] - bf2f(h0));
                unsigned short l1 = f2bf(pb[e] - bf2f(h1));
                *(unsigned*)&vtl[d*136 + j0] = (unsigned)l0 | ((unsigned)l1 << 16);
            }
        }
    }
    __syncthreads();

    // ---- P4: epilogue logits + in-register softmax ----
    float invc[8];
#pragma unroll
    for (int jt = 0; jt < 8; ++jt) invc[jt] = invn_s[jt*16 + ln];
    float p[8][4];
#pragma unroll
    for (int jt = 0; jt < 8; ++jt) {
        const int c = jt*16 + ln;
#pragma unroll
        for (int r = 0; r < 4; ++r) {
            const int i = wv*16 + g*4 + r;
            float val = accD[jt][r] * (scale * invc[jt]);
            if (c <= i) val += scale * bf2f(SB[i*134 + (127 + c - i)]);
            if (c == i) val = TOKEN_SELF;
            p[jt][r] = val;
        }
    }
#pragma unroll
    for (int r = 0; r < 4; ++r) {
        float m = p[0][r];
#pragma unroll
        for (int jt = 1; jt < 8; ++jt) m = fmaxf(m, p[jt][r]);
        m = fmaxf(m, __shfl_xor(m, 1));
        m = fmaxf(m, __shfl_xor(m, 2));
        m = fmaxf(m, __shfl_xor(m, 4));
        m = fmaxf(m, __shfl_xor(m, 8));
        float s = 0.f;
#pragma unroll
        for (int jt = 0; jt < 8; ++jt) {
            float e = __expf(p[jt][r] - m);
            p[jt][r] = e;
            s += e;
        }
        s += __shfl_xor(s, 1);
        s += __shfl_xor(s, 2);
        s += __shfl_xor(s, 4);
        s += __shfl_xor(s, 8);
        const float rs = 1.0f / s;
#pragma unroll
        for (int jt = 0; jt < 8; ++jt) p[jt][r] *= rs;
    }

    // ---- P5/P6: PV in two K-halves (P split hi/lo, V split hi/lo) ----
    f32x4 accO[4];
#pragma unroll
    for (int nt = 0; nt < 4; ++nt) accO[nt] = (f32x4)0.f;
    unsigned short* phi = SB;
    unsigned short* plo = SB + 9216;
    const unsigned short* vthc = SA;
    const unsigned short* vtlc = SA + 8704;
#pragma unroll
    for (int kh = 0; kh < 2; ++kh) {
        __syncthreads();   // kh=0: g2 reads done; kh=1: prior A-frag reads done
#pragma unroll
        for (int jtl = 0; jtl < 4; ++jtl) {
            const int jt = kh*4 + jtl;
#pragma unroll
            for (int r = 0; r < 4; ++r) {
                const int i = wv*16 + g*4 + r;
                const int cs = (jtl*16 + ln) ^ (((i >> 2) & 3) << 3);
                const float pv = p[jt][r];
                const unsigned short hb = f2bf(pv);
                phi[i*72 + cs] = hb;
                plo[i*72 + cs] = f2bf(pv - bf2f(hb));
            }
        }
        __syncthreads();
        __builtin_amdgcn_s_setprio(1);
#pragma unroll
        for (int kc = 0; kc < 2; ++kc) {
            const int i = wv*16 + ln;
            const int jb = (kc*32 + g*8) ^ (((ln >> 2) & 3) << 3);
            short8 aPh = *(const short8*)&phi[i*72 + jb];
            short8 aPl = *(const short8*)&plo[i*72 + jb];
#pragma unroll
            for (int nt = 0; nt < 4; ++nt) {
                const int vo = (nt*16 + ln)*136 + kh*64 + kc*32 + g*8;
                short8 bh_ = *(const short8*)&vthc[vo];
                short8 bl_ = *(const short8*)&vtlc[vo];
                f32x4 o = accO[nt];
                o = __builtin_amdgcn_mfma_f32_16x16x32_bf16(aPh, bh_, o, 0, 0, 0);
                o = __builtin_amdgcn_mfma_f32_16x16x32_bf16(aPh, bl_, o, 0, 0, 0);
                o = __builtin_amdgcn_mfma_f32_16x16x32_bf16(aPl, bh_, o, 0, 0, 0);
                accO[nt] = o;
            }
        }
        __builtin_amdgcn_s_setprio(0);
    }

    // ---- P7: plain store of window output ----
    float* dst = so + ((size_t)lb << 13);
#pragma unroll
    for (int nt = 0; nt < 4; ++nt)
#pragma unroll
        for (int r = 0; r < 4; ++r) {
            const int i = wv*16 + g*4 + r;
            dst[(i << 6) + nt*16 + ln] = accO[nt][r];
        }
}

// ---------------- Kernel F: per-token gather + mean (cnt/plist) ----------------
__global__ __launch_bounds__(256) void gather_kernel(const float* __restrict__ so,
                                                     const unsigned short* __restrict__ plist,
                                                     const int* __restrict__ cntp,
                                                     float* __restrict__ out) {
    const int lb = ((blockIdx.x & 7) << 12) + (blockIdx.x >> 3);  // XCD swizzle (32768)
    const int wid = (lb << 2) + (threadIdx.x >> 6);  // token id [0, 131072)
    const int lane = threadIdx.x & 63;
    const int bh = wid >> 13;
    const int tk = wid & 8191;
    const int n = cntp[(bh << 13) + tk];
    float acc = 0.f;
    const float* sob = so + ((size_t)bh << 19);
    const unsigned short* pl = plist + (((size_t)(bh << 13) + tk) << 6);
    for (int e = 0; e < n; ++e) {
        const int p = pl[e];
        acc += sob[((size_t)p << 6) + lane];
    }
    out[((size_t)wid << 6) + lane] = acc / ((float)n + 1e-5f);
}

extern "C" void kernel_launch(void* const* d_in, const int* in_sizes, int n_in,
                              void* d_out, int out_size, void* d_ws, size_t ws_size,
                              hipStream_t stream) {
    const float* qk    = (const float*)d_in[0];
    const float* vv    = (const float*)d_in[1];
    const float* means = (const float*)d_in[2];
    const float* relw  = (const float*)d_in[3];
    float* out = (float*)d_out;

    // ws layout: [keys u32 | so f32] 33.5MB (aliased), idx 0.5MB,
    //            plist u16 16.8MB, cnt 0.5MB  => 51.3MB total
    char* wsb = (char*)d_ws;
    const size_t keyBytes   = (size_t)16 * 64 * 8192 * 4;    // 33,554,432
    const size_t idxBytes   = (size_t)16 * 8192 * 4;         // 524,288
    const size_t plistBytes = (size_t)16 * 8192 * 64 * 2;    // 16,777,216
    unsigned* keys        = (unsigned*)wsb;
    float* so             = (float*)wsb;
    int* idxp             = (int*)(wsb + keyBytes);
    unsigned short* plist = (unsigned short*)(wsb + keyBytes + idxBytes);
    int* cntp             = (int*)(wsb + keyBytes + idxBytes + plistBytes);

    dists_kernel<<<1024, 512, 0, stream>>>(qk, means, keys, cntp);
    topk_kernel<<<1024, 256, 0, stream>>>(keys, idxp, plist, cntp);
    attn_kernel<<<1024, 512, 0, stream>>>(qk, vv, relw, idxp, so);
    gather_kernel<<<32768, 256, 0, stream>>>(so, plist, cntp, out);
}